// Round 2
// baseline (794.529 us; speedup 1.0000x reference)
//
#include <hip/hip_runtime.h>

typedef unsigned short u16;
typedef unsigned int u32;

constexpr int NN = 100000;   // nodes
constexpr int NE = 1600000;  // edges
constexpr int H = 128;       // hidden

constexpr int NB = 196;      // coarse buckets: b = dst >> 9 (512 nodes/bucket)
constexpr int BCAP = 10240;  // per-bucket capacity (mean 8192, +22 sigma)
constexpr int PB_E = 4096;   // edges per partition block
constexpr int PB_BLOCKS = (NE + PB_E - 1) / PB_E;  // 391

typedef __bf16 bf16x8 __attribute__((ext_vector_type(8)));
typedef float f32x16 __attribute__((ext_vector_type(16)));

__device__ __forceinline__ u16 f2bf(float f) {
    union { float f; u32 u; } cv; cv.f = f;
    u32 r = (cv.u + 0x7fffu + ((cv.u >> 16) & 1u)) >> 16;
    return (u16)r;
}
__device__ __forceinline__ float bflo(u32 u) {
    union { u32 u; float f; } cv; cv.u = u << 16; return cv.f;
}
__device__ __forceinline__ float bfhi(u32 u) {
    union { u32 u; float f; } cv; cv.u = u & 0xffff0000u; return cv.f;
}

// ---- detect int64 vs int32 edge storage -------------------------------------
__global__ void detect_kernel(const int* __restrict__ e, int* __restrict__ flag,
                              int* __restrict__ gcursor) {
    __shared__ int anynz;
    if (threadIdx.x == 0) anynz = 0;
    __syncthreads();
    int local = 0;
    for (int i = threadIdx.x; i < 4096; i += 256)
        if (e[2 * i + 1] != 0) local = 1;
    if (local) atomicOr(&anynz, 1);
    __syncthreads();
    if (threadIdx.x == 0) flag[0] = anynz ? 1 : 2;  // stride in int32 units
    if (threadIdx.x < NB) gcursor[threadIdx.x] = 0;
}

// ---- partition edges into NB dst-buckets (packed src|ldst) -------------------
__global__ __launch_bounds__(256) void part_kernel(const int* __restrict__ e,
                                                   const int* __restrict__ flag,
                                                   int* __restrict__ gcursor,
                                                   u32* __restrict__ ebuf) {
    __shared__ int lcnt[NB];
    __shared__ int gbaseL[NB];
    const int t = threadIdx.x;
    if (t < NB) lcnt[t] = 0;
    __syncthreads();
    const int st = flag[0];
    const int base = blockIdx.x * PB_E;
    u32 pk[16]; int bk[16]; int rk[16];
#pragma unroll
    for (int j = 0; j < 16; ++j) {
        int i = base + j * 256 + t;
        bk[j] = -1;
        if (i < NE) {
            int s = e[st * i];
            int d = e[st * (NE + i)];
            int b = d >> 9;
            pk[j] = (u32)s | ((u32)(d & 511) << 17);
            bk[j] = b;
            rk[j] = atomicAdd(&lcnt[b], 1);
        }
    }
    __syncthreads();
    if (t < NB) gbaseL[t] = atomicAdd(&gcursor[t], lcnt[t]);
    __syncthreads();
#pragma unroll
    for (int j = 0; j < 16; ++j)
        if (bk[j] >= 0)
            ebuf[bk[j] * BCAP + gbaseL[bk[j]] + rk[j]] = pk[j];
}

// ---- exclusive scan of bucket totals ----------------------------------------
__global__ __launch_bounds__(256) void bscan_kernel(const int* __restrict__ gcursor,
                                                    int* __restrict__ bbase,
                                                    int* __restrict__ offs) {
    __shared__ int s[256];
    int t = threadIdx.x;
    int v = (t < NB) ? gcursor[t] : 0;
    s[t] = v;
    __syncthreads();
    for (int off = 1; off < 256; off <<= 1) {
        int u = (t >= off) ? s[t - off] : 0;
        __syncthreads();
        s[t] += u;
        __syncthreads();
    }
    if (t < NB) bbase[t] = s[t] - v;
    if (t == 0) offs[NN] = NE;
}

// ---- per-bucket CSR fill: LDS node counts/scan/cursors, local colv scatter ---
__global__ __launch_bounds__(256) void bfill_kernel(const u32* __restrict__ ebuf,
                                                    const int* __restrict__ gcursor,
                                                    const int* __restrict__ bbase,
                                                    int* __restrict__ offs,
                                                    int* __restrict__ colv) {
    __shared__ int ncnt[512];
    __shared__ int cur[512];
    __shared__ int ps[256];
    const int b = blockIdx.x, t = threadIdx.x;
    const int En = gcursor[b];
    const int bb = bbase[b];
    ncnt[t] = 0; ncnt[t + 256] = 0;
    __syncthreads();
    const u32* eb = ebuf + b * BCAP;
    for (int i = t; i < En; i += 256)
        atomicAdd(&ncnt[eb[i] >> 17], 1);
    __syncthreads();
    int s2 = ncnt[2 * t] + ncnt[2 * t + 1];
    ps[t] = s2;
    __syncthreads();
    for (int off = 1; off < 256; off <<= 1) {
        int u = (t >= off) ? ps[t - off] : 0;
        __syncthreads();
        ps[t] += u;
        __syncthreads();
    }
    int e0 = ps[t] - s2;  // exclusive
    cur[2 * t] = e0;
    cur[2 * t + 1] = e0 + ncnt[2 * t];
    __syncthreads();
    const int n0 = b * 512;
    for (int i = t; i < 512; i += 256)
        if (n0 + i < NN) offs[n0 + i] = bb + cur[i];
    __syncthreads();  // offs reads of cur[] complete before pass2 mutates
    for (int i = t; i < En; i += 256) {
        u32 p = eb[i];
        int pos = atomicAdd(&cur[p >> 17], 1);
        colv[bb + pos] = (int)(p & 0x1FFFFu);
    }
}

// ---- transpose+convert weights: Wt[l*2+s][n][k] = W[l][k][n] (bf16) ---------
__global__ void wtconv_kernel(const float* __restrict__ W1,
                              const float* __restrict__ W2,
                              u16* __restrict__ wt) {
    int t = blockIdx.x * 256 + threadIdx.x;  // 131072 threads
    int w = t >> 14;      // 0..7 = l*2+s
    int r = t & 16383;
    int k = r >> 7, n = r & 127;  // n fastest -> coalesced reads
    int l = w >> 1, s = w & 1;
    const float* src = (s == 0 ? W1 : W2) + l * 16384;
    wt[w * 16384 + n * 128 + k] = f2bf(src[k * 128 + n]);
}

// ---- x init: copy fp32 x -> d_out, make bf16 shadow -------------------------
__global__ void xinit_kernel(const float* __restrict__ xin,
                             float* __restrict__ x, u16* __restrict__ xb) {
    int i = blockIdx.x * 256 + threadIdx.x;  // NN*H/4 threads
    float4 v = ((const float4*)xin)[i];
    ((float4*)x)[i] = v;
    uint2 p;
    p.x = (u32)f2bf(v.x) | ((u32)f2bf(v.y) << 16);
    p.y = (u32)f2bf(v.z) | ((u32)f2bf(v.w) << 16);
    ((uint2*)xb)[i] = p;
}

// ---- fused layer: agg (gather into LDS) + MLP + residual --------------------
// R7: agg_kernel fused into mlp_kernel. Rationale (R6 post-mortem): standalone
// agg is throughput-capped at ~3.7 TB/s on the L2-miss path (8 XCDs x 25.6MB
// structural re-fetch of xb) while VALU/MFMA idle; standalone mlp is the
// reverse. Fused, co-resident blocks at different phases overlap the two
// regimes, and the aggout round-trip (50MB/layer) disappears.
// xb is double-buffered (xbin read / xbout written) to avoid the cross-block
// race on xb rows.
__global__ __launch_bounds__(256) void mlp_kernel(const u16* __restrict__ xbin,
                                                  const int* __restrict__ colv,
                                                  const int* __restrict__ offs,
                                                  const u16* __restrict__ wt1,
                                                  const u16* __restrict__ wt2,
                                                  const float* __restrict__ b1,
                                                  const float* __restrict__ b2,
                                                  float* __restrict__ x,
                                                  u16* __restrict__ xbout) {
    __shared__ u16 lds[128 * 128];  // 32KB, XOR-swizzled 16B chunks
    const int tid = threadIdx.x;
    const int wave = tid >> 6, lane = tid & 63;
    const int wm = wave >> 1, wn = wave & 1;  // 2x2 wave grid, 64x64 per wave
    const int ml = lane & 31, g = lane >> 5;
    const int row0 = blockIdx.x * 128;

    // Phase 0: fused aggregation -> LDS A-tile (swizzled, bf16)
    // One wave per node (rows wave*32 .. wave*32+31), wave-uniform neighbor
    // indices via readfirstlane -> SGPR rowbase gathers (validated R4..R6).
    {
        const int s0 = wave * 32;
        for (int s = 0; s < 32; ++s) {
            const int r = s0 + s;
            const int node = row0 + r;
            float a0 = 0.f, a1 = 0.f;
            if (node < NN) {
                const int rs = __builtin_amdgcn_readfirstlane(offs[node]);
                const int re = __builtin_amdgcn_readfirstlane(offs[node + 1]);
                u32 su = *(const u32*)(xbin + node * H + lane * 2);
                a0 = bflo(su); a1 = bfhi(su);
                for (int j = rs; j < re; j += 8) {
                    int sidx[8];
#pragma unroll
                    for (int q = 0; q < 8; ++q) {
                        int idx = j + q;
                        idx = idx < re ? idx : re - 1;  // clamp: dup of last edge
                        sidx[q] = __builtin_amdgcn_readfirstlane(colv[idx]);
                    }
                    u32 uu[8];
#pragma unroll
                    for (int q = 0; q < 8; ++q)
                        uu[q] = *(const u32*)(xbin + sidx[q] * H + lane * 2);
#pragma unroll
                    for (int q = 0; q < 8; ++q) {
                        u32 m = (j + q < re) ? 0xffffffffu : 0u;  // wave-uniform
                        u32 u = uu[q] & m;
                        a0 += bflo(u); a1 += bfhi(u);
                    }
                }
            }
            // store u32 (2 bf16) at row r, byte offset lane*4, chunk-swizzled
            u32 o = (u32)f2bf(a0) | ((u32)f2bf(a1) << 16);
            *(u32*)(&lds[r * H + (((lane >> 2) ^ (r & 15)) << 3) + ((lane & 3) << 1)]) = o;
        }
    }

    // B1 fragments from global (L2-resident): B[k][n], n=ml, k=(g*8..)+j
    bf16x8 bfrag[2][8];
#pragma unroll
    for (int nt = 0; nt < 2; ++nt)
#pragma unroll
        for (int ks = 0; ks < 8; ++ks)
            bfrag[nt][ks] = *(const bf16x8*)(wt1 + (wn * 64 + nt * 32 + ml) * H + ks * 16 + g * 8);

    float bias1[2], bias2[2];
#pragma unroll
    for (int nt = 0; nt < 2; ++nt) {
        bias1[nt] = b1[wn * 64 + nt * 32 + ml];
        bias2[nt] = b2[wn * 64 + nt * 32 + ml];
    }

    __syncthreads();

    f32x16 acc[2][2];
#pragma unroll
    for (int mt = 0; mt < 2; ++mt)
#pragma unroll
        for (int nt = 0; nt < 2; ++nt)
#pragma unroll
            for (int i = 0; i < 16; ++i) acc[mt][nt][i] = 0.f;

    // GEMM1
#pragma unroll
    for (int ks = 0; ks < 8; ++ks) {
        bf16x8 afrag[2];
#pragma unroll
        for (int mt = 0; mt < 2; ++mt) {
            int m = wm * 64 + mt * 32 + ml;
            int chunk = (2 * ks + g) ^ (m & 15);
            afrag[mt] = *(const bf16x8*)(&lds[m * H + (chunk << 3)]);
        }
#pragma unroll
        for (int mt = 0; mt < 2; ++mt)
#pragma unroll
            for (int nt = 0; nt < 2; ++nt)
                acc[mt][nt] = __builtin_amdgcn_mfma_f32_32x32x16_bf16(
                    afrag[mt], bfrag[nt][ks], acc[mt][nt], 0, 0, 0);
    }

    __syncthreads();  // all A reads done before T overwrites LDS

    // T = relu(acc + b1) -> LDS (C-layout -> row-major[m][k], swizzled)
#pragma unroll
    for (int mt = 0; mt < 2; ++mt)
#pragma unroll
        for (int nt = 0; nt < 2; ++nt)
#pragma unroll
            for (int reg = 0; reg < 16; ++reg) {
                int rm = wm * 64 + mt * 32 + (reg & 3) + ((reg >> 2) << 3) + 4 * g;
                int cn = wn * 64 + nt * 32 + ml;
                float v = acc[mt][nt][reg] + bias1[nt];
                v = v > 0.f ? v : 0.f;
                lds[rm * H + ((((cn >> 3) ^ (rm & 15))) << 3) + (cn & 7)] = f2bf(v);
            }

    // B2 fragments
#pragma unroll
    for (int nt = 0; nt < 2; ++nt)
#pragma unroll
        for (int ks = 0; ks < 8; ++ks)
            bfrag[nt][ks] = *(const bf16x8*)(wt2 + (wn * 64 + nt * 32 + ml) * H + ks * 16 + g * 8);

#pragma unroll
    for (int mt = 0; mt < 2; ++mt)
#pragma unroll
        for (int nt = 0; nt < 2; ++nt)
#pragma unroll
            for (int i = 0; i < 16; ++i) acc[mt][nt][i] = 0.f;

    __syncthreads();

    // GEMM2
#pragma unroll
    for (int ks = 0; ks < 8; ++ks) {
        bf16x8 afrag[2];
#pragma unroll
        for (int mt = 0; mt < 2; ++mt) {
            int m = wm * 64 + mt * 32 + ml;
            int chunk = (2 * ks + g) ^ (m & 15);
            afrag[mt] = *(const bf16x8*)(&lds[m * H + (chunk << 3)]);
        }
#pragma unroll
        for (int mt = 0; mt < 2; ++mt)
#pragma unroll
            for (int nt = 0; nt < 2; ++nt)
                acc[mt][nt] = __builtin_amdgcn_mfma_f32_32x32x16_bf16(
                    afrag[mt], bfrag[nt][ks], acc[mt][nt], 0, 0, 0);
    }

    __syncthreads();  // all T reads done before h overwrites LDS

    // h = relu(acc + b2) -> LDS (same swizzle)
#pragma unroll
    for (int mt = 0; mt < 2; ++mt)
#pragma unroll
        for (int nt = 0; nt < 2; ++nt)
#pragma unroll
            for (int reg = 0; reg < 16; ++reg) {
                int rm = wm * 64 + mt * 32 + (reg & 3) + ((reg >> 2) << 3) + 4 * g;
                int cn = wn * 64 + nt * 32 + ml;
                float v = acc[mt][nt][reg] + bias2[nt];
                v = v > 0.f ? v : 0.f;
                lds[rm * H + ((((cn >> 3) ^ (rm & 15))) << 3) + (cn & 7)] = f2bf(v);
            }

    __syncthreads();

    // coalesced residual update: x += h; xbout = bf16(x)
#pragma unroll
    for (int i = 0; i < 8; ++i) {
        int ch = tid + 256 * i;
        int r = ch >> 4, c = ch & 15;
        int gr = row0 + r;
        if (gr < NN) {
            int4 hv = *(const int4*)(&lds[r * H + ((c ^ (r & 15)) << 3)]);
            float4 x0 = *(const float4*)(x + gr * H + c * 8);
            float4 x1 = *(const float4*)(x + gr * H + c * 8 + 4);
            x0.x += bflo((u32)hv.x); x0.y += bfhi((u32)hv.x);
            x0.z += bflo((u32)hv.y); x0.w += bfhi((u32)hv.y);
            x1.x += bflo((u32)hv.z); x1.y += bfhi((u32)hv.z);
            x1.z += bflo((u32)hv.w); x1.w += bfhi((u32)hv.w);
            *(float4*)(x + gr * H + c * 8) = x0;
            *(float4*)(x + gr * H + c * 8 + 4) = x1;
            int4 xo;
            xo.x = (int)((u32)f2bf(x0.x) | ((u32)f2bf(x0.y) << 16));
            xo.y = (int)((u32)f2bf(x0.z) | ((u32)f2bf(x0.w) << 16));
            xo.z = (int)((u32)f2bf(x1.x) | ((u32)f2bf(x1.y) << 16));
            xo.w = (int)((u32)f2bf(x1.z) | ((u32)f2bf(x1.w) << 16));
            *(int4*)(xbout + gr * H + c * 8) = xo;
        }
    }
}

extern "C" void kernel_launch(void* const* d_in, const int* in_sizes, int n_in,
                              void* d_out, int out_size, void* d_ws, size_t ws_size,
                              hipStream_t stream) {
    const float* x_in = (const float*)d_in[0];
    const int* edges = (const int*)d_in[1];
    const float* W1 = (const float*)d_in[2];
    const float* b1 = (const float*)d_in[3];
    const float* W2 = (const float*)d_in[4];
    const float* b2 = (const float*)d_in[5];
    float* x = (float*)d_out;

    char* ws = (char*)d_ws;
    int* flag = (int*)ws;                        // 4B        @ 0
    int* gcursor = (int*)(ws + 512);             // 784B      @ 512
    int* bbase = (int*)(ws + 2048);              // 784B      @ 2048
    int* offs = (int*)(ws + 4096);               // 400004B   @ 4096
    int* colv = (int*)(ws + 406528);             // 6400000B
    u16* wt = (u16*)(ws + 6809600);              // 262144B
    u16* xb0 = (u16*)(ws + 7072768);             // 25600000B
    u16* xb1 = (u16*)(ws + 32672768);            // 25600000B (end ~58.3MB)
    u32* ebuf = (u32*)xb1;                       // 8.03MB, dead before xb1 written

    detect_kernel<<<1, 256, 0, stream>>>(edges, flag, gcursor);
    part_kernel<<<PB_BLOCKS, 256, 0, stream>>>(edges, flag, gcursor, ebuf);
    bscan_kernel<<<1, 256, 0, stream>>>(gcursor, bbase, offs);
    bfill_kernel<<<NB, 256, 0, stream>>>(ebuf, gcursor, bbase, offs, colv);
    wtconv_kernel<<<131072 / 256, 256, 0, stream>>>(W1, W2, wt);
    xinit_kernel<<<(NN * H / 4) / 256, 256, 0, stream>>>(x_in, x, xb0);

    for (int l = 0; l < 4; ++l) {
        u16* xin = (l & 1) ? xb1 : xb0;
        u16* xout = (l & 1) ? xb0 : xb1;
        mlp_kernel<<<(NN + 127) / 128, 256, 0, stream>>>(
            xin, colv, offs,
            wt + (l * 2) * 16384, wt + (l * 2 + 1) * 16384,
            b1 + l * 128, b2 + l * 128, x, xout);
    }
}

// Round 3
// 524.214 us; speedup vs baseline: 1.5157x; 1.5157x over previous
//
#include <hip/hip_runtime.h>

typedef unsigned short u16;
typedef unsigned int u32;

constexpr int NN = 100000;   // nodes
constexpr int NE = 1600000;  // edges
constexpr int H = 128;       // hidden

constexpr int NB = 196;      // coarse buckets: b = dst >> 9 (512 nodes/bucket)
constexpr int BCAP = 10240;  // per-bucket capacity (mean 8192, +22 sigma)
constexpr int PB_E = 4096;   // edges per partition block
constexpr int PB_BLOCKS = (NE + PB_E - 1) / PB_E;  // 391

typedef __bf16 bf16x8 __attribute__((ext_vector_type(8)));
typedef float f32x16 __attribute__((ext_vector_type(16)));

__device__ __forceinline__ u16 f2bf(float f) {
    union { float f; u32 u; } cv; cv.f = f;
    u32 r = (cv.u + 0x7fffu + ((cv.u >> 16) & 1u)) >> 16;
    return (u16)r;
}
__device__ __forceinline__ float bflo(u32 u) {
    union { u32 u; float f; } cv; cv.u = u << 16; return cv.f;
}
__device__ __forceinline__ float bfhi(u32 u) {
    union { u32 u; float f; } cv; cv.u = u & 0xffff0000u; return cv.f;
}

// ---- detect int64 vs int32 edge storage -------------------------------------
__global__ void detect_kernel(const int* __restrict__ e, int* __restrict__ flag,
                              int* __restrict__ gcursor) {
    __shared__ int anynz;
    if (threadIdx.x == 0) anynz = 0;
    __syncthreads();
    int local = 0;
    for (int i = threadIdx.x; i < 4096; i += 256)
        if (e[2 * i + 1] != 0) local = 1;
    if (local) atomicOr(&anynz, 1);
    __syncthreads();
    if (threadIdx.x == 0) flag[0] = anynz ? 1 : 2;  // stride in int32 units
    if (threadIdx.x < NB) gcursor[threadIdx.x] = 0;
}

// ---- partition edges into NB dst-buckets (packed src|ldst) -------------------
__global__ __launch_bounds__(256) void part_kernel(const int* __restrict__ e,
                                                   const int* __restrict__ flag,
                                                   int* __restrict__ gcursor,
                                                   u32* __restrict__ ebuf) {
    __shared__ int lcnt[NB];
    __shared__ int gbaseL[NB];
    const int t = threadIdx.x;
    if (t < NB) lcnt[t] = 0;
    __syncthreads();
    const int st = flag[0];
    const int base = blockIdx.x * PB_E;
    u32 pk[16]; int bk[16]; int rk[16];
#pragma unroll
    for (int j = 0; j < 16; ++j) {
        int i = base + j * 256 + t;
        bk[j] = -1;
        if (i < NE) {
            int s = e[st * i];
            int d = e[st * (NE + i)];
            int b = d >> 9;
            pk[j] = (u32)s | ((u32)(d & 511) << 17);
            bk[j] = b;
            rk[j] = atomicAdd(&lcnt[b], 1);
        }
    }
    __syncthreads();
    if (t < NB) gbaseL[t] = atomicAdd(&gcursor[t], lcnt[t]);
    __syncthreads();
#pragma unroll
    for (int j = 0; j < 16; ++j)
        if (bk[j] >= 0)
            ebuf[bk[j] * BCAP + gbaseL[bk[j]] + rk[j]] = pk[j];
}

// ---- exclusive scan of bucket totals ----------------------------------------
__global__ __launch_bounds__(256) void bscan_kernel(const int* __restrict__ gcursor,
                                                    int* __restrict__ bbase,
                                                    int* __restrict__ offs) {
    __shared__ int s[256];
    int t = threadIdx.x;
    int v = (t < NB) ? gcursor[t] : 0;
    s[t] = v;
    __syncthreads();
    for (int off = 1; off < 256; off <<= 1) {
        int u = (t >= off) ? s[t - off] : 0;
        __syncthreads();
        s[t] += u;
        __syncthreads();
    }
    if (t < NB) bbase[t] = s[t] - v;
    if (t == 0) offs[NN] = NE;
}

// ---- per-bucket CSR fill: LDS node counts/scan/cursors, local colv scatter ---
__global__ __launch_bounds__(256) void bfill_kernel(const u32* __restrict__ ebuf,
                                                    const int* __restrict__ gcursor,
                                                    const int* __restrict__ bbase,
                                                    int* __restrict__ offs,
                                                    int* __restrict__ colv) {
    __shared__ int ncnt[512];
    __shared__ int cur[512];
    __shared__ int ps[256];
    const int b = blockIdx.x, t = threadIdx.x;
    const int En = gcursor[b];
    const int bb = bbase[b];
    ncnt[t] = 0; ncnt[t + 256] = 0;
    __syncthreads();
    const u32* eb = ebuf + b * BCAP;
    for (int i = t; i < En; i += 256)
        atomicAdd(&ncnt[eb[i] >> 17], 1);
    __syncthreads();
    int s2 = ncnt[2 * t] + ncnt[2 * t + 1];
    ps[t] = s2;
    __syncthreads();
    for (int off = 1; off < 256; off <<= 1) {
        int u = (t >= off) ? ps[t - off] : 0;
        __syncthreads();
        ps[t] += u;
        __syncthreads();
    }
    int e0 = ps[t] - s2;  // exclusive
    cur[2 * t] = e0;
    cur[2 * t + 1] = e0 + ncnt[2 * t];
    __syncthreads();
    const int n0 = b * 512;
    for (int i = t; i < 512; i += 256)
        if (n0 + i < NN) offs[n0 + i] = bb + cur[i];
    __syncthreads();  // offs reads of cur[] complete before pass2 mutates
    for (int i = t; i < En; i += 256) {
        u32 p = eb[i];
        int pos = atomicAdd(&cur[p >> 17], 1);
        colv[bb + pos] = (int)(p & 0x1FFFFu);
    }
}

// ---- transpose+convert weights: Wt[l*2+s][n][k] = W[l][k][n] (bf16) ---------
__global__ void wtconv_kernel(const float* __restrict__ W1,
                              const float* __restrict__ W2,
                              u16* __restrict__ wt) {
    int t = blockIdx.x * 256 + threadIdx.x;  // 131072 threads
    int w = t >> 14;      // 0..7 = l*2+s
    int r = t & 16383;
    int k = r >> 7, n = r & 127;  // n fastest -> coalesced reads
    int l = w >> 1, s = w & 1;
    const float* src = (s == 0 ? W1 : W2) + l * 16384;
    wt[w * 16384 + n * 128 + k] = f2bf(src[k * 128 + n]);
}

// ---- x init: copy fp32 x -> d_out, make bf16 shadow -------------------------
__global__ void xinit_kernel(const float* __restrict__ xin,
                             float* __restrict__ x, u16* __restrict__ xb) {
    int i = blockIdx.x * 256 + threadIdx.x;  // NN*H/4 threads
    float4 v = ((const float4*)xin)[i];
    ((float4*)x)[i] = v;
    uint2 p;
    p.x = (u32)f2bf(v.x) | ((u32)f2bf(v.y) << 16);
    p.y = (u32)f2bf(v.z) | ((u32)f2bf(v.w) << 16);
    ((uint2*)xb)[i] = p;
}

// ---- fused layer: agg (gather into LDS) + MLP + residual --------------------
// R8: fusion retained but tile shrunk 4x (R7 post-mortem: 782-block grid = 3
// blocks/CU + 32-node serial gather per wave starved TLP; occupancy 16%).
// Now BM=32 rows, grid=3125 (NN exactly), 8 KB LDS, one 32x32 MFMA tile per
// wave, ~6 blocks/CU resident -> gather TLP matches the standalone agg kernel
// while MFMA/stream phases of other blocks overlap the gather-capped path.
__global__ __launch_bounds__(256) void mlp_kernel(const u16* __restrict__ xbin,
                                                  const int* __restrict__ colv,
                                                  const int* __restrict__ offs,
                                                  const u16* __restrict__ wt1,
                                                  const u16* __restrict__ wt2,
                                                  const float* __restrict__ b1,
                                                  const float* __restrict__ b2,
                                                  float* __restrict__ x,
                                                  u16* __restrict__ xbout) {
    __shared__ u16 lds[32 * 128];  // 8 KB, XOR-swizzled 16B chunks
    const int tid = threadIdx.x;
    const int wave = tid >> 6, lane = tid & 63;
    const int ml = lane & 31, g = lane >> 5;
    const int row0 = blockIdx.x * 32;  // NN = 3125*32 exactly, no tail

    // Phase 0: fused aggregation -> LDS A-tile (swizzled, bf16)
    // wave w gathers rows w*8 .. w*8+7 (8 nodes serial, 8-deep edge batches,
    // wave-uniform neighbor indices via readfirstlane -> SGPR rowbase).
    {
        const int s0 = wave * 8;
        for (int s = 0; s < 8; ++s) {
            const int r = s0 + s;
            const int node = row0 + r;
            const int rs = __builtin_amdgcn_readfirstlane(offs[node]);
            const int re = __builtin_amdgcn_readfirstlane(offs[node + 1]);
            u32 su = *(const u32*)(xbin + node * H + lane * 2);
            float a0 = bflo(su), a1 = bfhi(su);
            for (int j = rs; j < re; j += 8) {
                int sidx[8];
#pragma unroll
                for (int q = 0; q < 8; ++q) {
                    int idx = j + q;
                    idx = idx < re ? idx : re - 1;  // clamp: dup of last edge
                    sidx[q] = __builtin_amdgcn_readfirstlane(colv[idx]);
                }
                u32 uu[8];
#pragma unroll
                for (int q = 0; q < 8; ++q)
                    uu[q] = *(const u32*)(xbin + sidx[q] * H + lane * 2);
#pragma unroll
                for (int q = 0; q < 8; ++q) {
                    u32 m = (j + q < re) ? 0xffffffffu : 0u;  // wave-uniform
                    u32 u = uu[q] & m;
                    a0 += bflo(u); a1 += bfhi(u);
                }
            }
            // store u32 (2 bf16) at row r, chunk-swizzled
            u32 o = (u32)f2bf(a0) | ((u32)f2bf(a1) << 16);
            *(u32*)(&lds[r * H + (((lane >> 2) ^ (r & 15)) << 3) + ((lane & 3) << 1)]) = o;
        }
    }

    // B1 fragments from global (L2-resident): B[k][n], n = wave*32+ml
    bf16x8 bfrag[8];
#pragma unroll
    for (int ks = 0; ks < 8; ++ks)
        bfrag[ks] = *(const bf16x8*)(wt1 + (wave * 32 + ml) * H + ks * 16 + g * 8);

    const float bias1 = b1[wave * 32 + ml];
    const float bias2 = b2[wave * 32 + ml];

    __syncthreads();

    f32x16 acc;
#pragma unroll
    for (int i = 0; i < 16; ++i) acc[i] = 0.f;

    // GEMM1: C[0:32][wave*32 .. +32]
#pragma unroll
    for (int ks = 0; ks < 8; ++ks) {
        int chunk = (2 * ks + g) ^ (ml & 15);
        bf16x8 afrag = *(const bf16x8*)(&lds[ml * H + (chunk << 3)]);
        acc = __builtin_amdgcn_mfma_f32_32x32x16_bf16(afrag, bfrag[ks], acc, 0, 0, 0);
    }

    __syncthreads();  // all A reads done before T overwrites LDS

    // T = relu(acc + b1) -> LDS (C-layout -> row-major[m][k], swizzled)
#pragma unroll
    for (int reg = 0; reg < 16; ++reg) {
        int rm = (reg & 3) + ((reg >> 2) << 3) + 4 * g;   // 0..31
        int cn = wave * 32 + ml;                           // 0..127
        float v = acc[reg] + bias1;
        v = v > 0.f ? v : 0.f;
        lds[rm * H + ((((cn >> 3) ^ (rm & 15))) << 3) + (cn & 7)] = f2bf(v);
    }

    // B2 fragments
#pragma unroll
    for (int ks = 0; ks < 8; ++ks)
        bfrag[ks] = *(const bf16x8*)(wt2 + (wave * 32 + ml) * H + ks * 16 + g * 8);

#pragma unroll
    for (int i = 0; i < 16; ++i) acc[i] = 0.f;

    __syncthreads();

    // GEMM2
#pragma unroll
    for (int ks = 0; ks < 8; ++ks) {
        int chunk = (2 * ks + g) ^ (ml & 15);
        bf16x8 afrag = *(const bf16x8*)(&lds[ml * H + (chunk << 3)]);
        acc = __builtin_amdgcn_mfma_f32_32x32x16_bf16(afrag, bfrag[ks], acc, 0, 0, 0);
    }

    __syncthreads();  // all T reads done before h overwrites LDS

    // h = relu(acc + b2) -> LDS (same swizzle)
#pragma unroll
    for (int reg = 0; reg < 16; ++reg) {
        int rm = (reg & 3) + ((reg >> 2) << 3) + 4 * g;
        int cn = wave * 32 + ml;
        float v = acc[reg] + bias2;
        v = v > 0.f ? v : 0.f;
        lds[rm * H + ((((cn >> 3) ^ (rm & 15))) << 3) + (cn & 7)] = f2bf(v);
    }

    __syncthreads();

    // coalesced residual update: x += h; xbout = bf16(x)
    // 32 rows x 16 chunks = 512 tasks, 2 per thread
#pragma unroll
    for (int i = 0; i < 2; ++i) {
        int ch = tid + 256 * i;
        int r = ch >> 4, c = ch & 15;
        int gr = row0 + r;
        int4 hv = *(const int4*)(&lds[r * H + ((c ^ (r & 15)) << 3)]);
        float4 x0 = *(const float4*)(x + gr * H + c * 8);
        float4 x1 = *(const float4*)(x + gr * H + c * 8 + 4);
        x0.x += bflo((u32)hv.x); x0.y += bfhi((u32)hv.x);
        x0.z += bflo((u32)hv.y); x0.w += bfhi((u32)hv.y);
        x1.x += bflo((u32)hv.z); x1.y += bfhi((u32)hv.z);
        x1.z += bflo((u32)hv.w); x1.w += bfhi((u32)hv.w);
        *(float4*)(x + gr * H + c * 8) = x0;
        *(float4*)(x + gr * H + c * 8 + 4) = x1;
        int4 xo;
        xo.x = (int)((u32)f2bf(x0.x) | ((u32)f2bf(x0.y) << 16));
        xo.y = (int)((u32)f2bf(x0.z) | ((u32)f2bf(x0.w) << 16));
        xo.z = (int)((u32)f2bf(x1.x) | ((u32)f2bf(x1.y) << 16));
        xo.w = (int)((u32)f2bf(x1.z) | ((u32)f2bf(x1.w) << 16));
        *(int4*)(xbout + gr * H + c * 8) = xo;
    }
}

extern "C" void kernel_launch(void* const* d_in, const int* in_sizes, int n_in,
                              void* d_out, int out_size, void* d_ws, size_t ws_size,
                              hipStream_t stream) {
    const float* x_in = (const float*)d_in[0];
    const int* edges = (const int*)d_in[1];
    const float* W1 = (const float*)d_in[2];
    const float* b1 = (const float*)d_in[3];
    const float* W2 = (const float*)d_in[4];
    const float* b2 = (const float*)d_in[5];
    float* x = (float*)d_out;

    char* ws = (char*)d_ws;
    int* flag = (int*)ws;                        // 4B        @ 0
    int* gcursor = (int*)(ws + 512);             // 784B      @ 512
    int* bbase = (int*)(ws + 2048);              // 784B      @ 2048
    int* offs = (int*)(ws + 4096);               // 400004B   @ 4096
    int* colv = (int*)(ws + 406528);             // 6400000B
    u16* wt = (u16*)(ws + 6809600);              // 262144B
    u16* xb0 = (u16*)(ws + 7072768);             // 25600000B
    u16* xb1 = (u16*)(ws + 32672768);            // 25600000B (end ~58.3MB)
    u32* ebuf = (u32*)xb1;                       // 8.03MB, dead before xb1 written

    detect_kernel<<<1, 256, 0, stream>>>(edges, flag, gcursor);
    part_kernel<<<PB_BLOCKS, 256, 0, stream>>>(edges, flag, gcursor, ebuf);
    bscan_kernel<<<1, 256, 0, stream>>>(gcursor, bbase, offs);
    bfill_kernel<<<NB, 256, 0, stream>>>(ebuf, gcursor, bbase, offs, colv);
    wtconv_kernel<<<131072 / 256, 256, 0, stream>>>(W1, W2, wt);
    xinit_kernel<<<(NN * H / 4) / 256, 256, 0, stream>>>(x_in, x, xb0);

    for (int l = 0; l < 4; ++l) {
        u16* xin = (l & 1) ? xb1 : xb0;
        u16* xout = (l & 1) ? xb0 : xb1;
        mlp_kernel<<<NN / 32, 256, 0, stream>>>(
            xin, colv, offs,
            wt + (l * 2) * 16384, wt + (l * 2 + 1) * 16384,
            b1 + l * 128, b2 + l * 128, x, xout);
    }
}

// Round 4
// 490.063 us; speedup vs baseline: 1.6213x; 1.0697x over previous
//
#include <hip/hip_runtime.h>

typedef unsigned short u16;
typedef unsigned int u32;

constexpr int NN = 100000;   // nodes
constexpr int NE = 1600000;  // edges
constexpr int H = 128;       // hidden

constexpr int NB = 196;      // coarse buckets: b = dst >> 9 (512 nodes/bucket)
constexpr int BCAP = 10240;  // per-bucket capacity (mean 8192, +22 sigma)
constexpr int PB_E = 4096;   // edges per partition block
constexpr int PB_BLOCKS = (NE + PB_E - 1) / PB_E;  // 391

typedef __bf16 bf16x8 __attribute__((ext_vector_type(8)));
typedef float f32x16 __attribute__((ext_vector_type(16)));

__device__ __forceinline__ u16 f2bf(float f) {
    union { float f; u32 u; } cv; cv.f = f;
    u32 r = (cv.u + 0x7fffu + ((cv.u >> 16) & 1u)) >> 16;
    return (u16)r;
}
__device__ __forceinline__ float bflo(u32 u) {
    union { u32 u; float f; } cv; cv.u = u << 16; return cv.f;
}
__device__ __forceinline__ float bfhi(u32 u) {
    union { u32 u; float f; } cv; cv.u = u & 0xffff0000u; return cv.f;
}

// ---- detect int64 vs int32 edge storage -------------------------------------
__global__ void detect_kernel(const int* __restrict__ e, int* __restrict__ flag,
                              int* __restrict__ gcursor) {
    __shared__ int anynz;
    if (threadIdx.x == 0) anynz = 0;
    __syncthreads();
    int local = 0;
    for (int i = threadIdx.x; i < 4096; i += 256)
        if (e[2 * i + 1] != 0) local = 1;
    if (local) atomicOr(&anynz, 1);
    __syncthreads();
    if (threadIdx.x == 0) flag[0] = anynz ? 1 : 2;  // stride in int32 units
    if (threadIdx.x < NB) gcursor[threadIdx.x] = 0;
}

// ---- partition edges into NB dst-buckets (packed src|ldst) -------------------
__global__ __launch_bounds__(256) void part_kernel(const int* __restrict__ e,
                                                   const int* __restrict__ flag,
                                                   int* __restrict__ gcursor,
                                                   u32* __restrict__ ebuf) {
    __shared__ int lcnt[NB];
    __shared__ int gbaseL[NB];
    const int t = threadIdx.x;
    if (t < NB) lcnt[t] = 0;
    __syncthreads();
    const int st = flag[0];
    const int base = blockIdx.x * PB_E;
    u32 pk[16]; int bk[16]; int rk[16];
#pragma unroll
    for (int j = 0; j < 16; ++j) {
        int i = base + j * 256 + t;
        bk[j] = -1;
        if (i < NE) {
            int s = e[st * i];
            int d = e[st * (NE + i)];
            int b = d >> 9;
            pk[j] = (u32)s | ((u32)(d & 511) << 17);
            bk[j] = b;
            rk[j] = atomicAdd(&lcnt[b], 1);
        }
    }
    __syncthreads();
    if (t < NB) gbaseL[t] = atomicAdd(&gcursor[t], lcnt[t]);
    __syncthreads();
#pragma unroll
    for (int j = 0; j < 16; ++j)
        if (bk[j] >= 0)
            ebuf[bk[j] * BCAP + gbaseL[bk[j]] + rk[j]] = pk[j];
}

// ---- exclusive scan of bucket totals ----------------------------------------
__global__ __launch_bounds__(256) void bscan_kernel(const int* __restrict__ gcursor,
                                                    int* __restrict__ bbase,
                                                    int* __restrict__ offs) {
    __shared__ int s[256];
    int t = threadIdx.x;
    int v = (t < NB) ? gcursor[t] : 0;
    s[t] = v;
    __syncthreads();
    for (int off = 1; off < 256; off <<= 1) {
        int u = (t >= off) ? s[t - off] : 0;
        __syncthreads();
        s[t] += u;
        __syncthreads();
    }
    if (t < NB) bbase[t] = s[t] - v;
    if (t == 0) offs[NN] = NE;
}

// ---- per-bucket CSR fill: LDS node counts/scan/cursors, local colv scatter ---
// R9: colv entry now packs src (bits 0..16) and tile-local dst row (bits 27..31,
// = dst & 31 for the BM=32 tiles) so the fused gather can route each edge to its
// LDS row with wave-uniform scalar ops.
__global__ __launch_bounds__(256) void bfill_kernel(const u32* __restrict__ ebuf,
                                                    const int* __restrict__ gcursor,
                                                    const int* __restrict__ bbase,
                                                    int* __restrict__ offs,
                                                    int* __restrict__ colv) {
    __shared__ int ncnt[512];
    __shared__ int cur[512];
    __shared__ int ps[256];
    const int b = blockIdx.x, t = threadIdx.x;
    const int En = gcursor[b];
    const int bb = bbase[b];
    ncnt[t] = 0; ncnt[t + 256] = 0;
    __syncthreads();
    const u32* eb = ebuf + b * BCAP;
    for (int i = t; i < En; i += 256)
        atomicAdd(&ncnt[eb[i] >> 17], 1);
    __syncthreads();
    int s2 = ncnt[2 * t] + ncnt[2 * t + 1];
    ps[t] = s2;
    __syncthreads();
    for (int off = 1; off < 256; off <<= 1) {
        int u = (t >= off) ? ps[t - off] : 0;
        __syncthreads();
        ps[t] += u;
        __syncthreads();
    }
    int e0 = ps[t] - s2;  // exclusive
    cur[2 * t] = e0;
    cur[2 * t + 1] = e0 + ncnt[2 * t];
    __syncthreads();
    const int n0 = b * 512;
    for (int i = t; i < 512; i += 256)
        if (n0 + i < NN) offs[n0 + i] = bb + cur[i];
    __syncthreads();  // offs reads of cur[] complete before pass2 mutates
    for (int i = t; i < En; i += 256) {
        u32 p = eb[i];
        int pos = atomicAdd(&cur[p >> 17], 1);
        colv[bb + pos] = (int)((p & 0x1FFFFu) | (((p >> 17) & 31u) << 27));
    }
}

// ---- transpose+convert weights: Wt[l*2+s][n][k] = W[l][k][n] (bf16) ---------
__global__ void wtconv_kernel(const float* __restrict__ W1,
                              const float* __restrict__ W2,
                              u16* __restrict__ wt) {
    int t = blockIdx.x * 256 + threadIdx.x;  // 131072 threads
    int w = t >> 14;      // 0..7 = l*2+s
    int r = t & 16383;
    int k = r >> 7, n = r & 127;  // n fastest -> coalesced reads
    int l = w >> 1, s = w & 1;
    const float* src = (s == 0 ? W1 : W2) + l * 16384;
    wt[w * 16384 + n * 128 + k] = f2bf(src[k * 128 + n]);
}

// ---- x init: copy fp32 x -> d_out, make bf16 shadow -------------------------
__global__ void xinit_kernel(const float* __restrict__ xin,
                             float* __restrict__ x, u16* __restrict__ xb) {
    int i = blockIdx.x * 256 + threadIdx.x;  // NN*H/4 threads
    float4 v = ((const float4*)xin)[i];
    ((float4*)x)[i] = v;
    uint2 p;
    p.x = (u32)f2bf(v.x) | ((u32)f2bf(v.y) << 16);
    p.y = (u32)f2bf(v.z) | ((u32)f2bf(v.w) << 16);
    ((uint2*)xb)[i] = p;
}

// ---- fused layer: agg (gather into LDS) + MLP + residual --------------------
// R9 gather rewrite (R8 post-mortem: 93us/layer @3.2TB/s < the 79us floor at
// the demonstrated 3.7TB/s gather rate; per-wave MLP too shallow):
//  * LDS tile pre-filled with self rows (streaming int4, replaces per-node su).
//  * A wave's 8 nodes have CONTIGUOUS CSR ranges -> gather the flat edge range
//    16-deep per window (~8 windows/wave vs ~18 with per-node 8-deep batches).
//    Per-edge dst row comes from colv bits 27..31; routing + flush to LDS is
//    wave-uniform (rows monotone within the range -> each row flushed once).
//  * colv entries for window j+1 prefetched while window j's rows are in
//    flight -> one memory latency per window instead of two.
__global__ __launch_bounds__(256) void mlp_kernel(const u16* __restrict__ xbin,
                                                  const int* __restrict__ colv,
                                                  const int* __restrict__ offs,
                                                  const u16* __restrict__ wt1,
                                                  const u16* __restrict__ wt2,
                                                  const float* __restrict__ b1,
                                                  const float* __restrict__ b2,
                                                  float* __restrict__ x,
                                                  u16* __restrict__ xbout) {
    __shared__ u16 lds[32 * 128];  // 8 KB, XOR-swizzled 16B chunks
    const int tid = threadIdx.x;
    const int wave = tid >> 6, lane = tid & 63;
    const int ml = lane & 31, g = lane >> 5;
    const int row0 = blockIdx.x * 32;  // NN = 3125*32 exactly, no tail

    // Phase 0a: self rows -> LDS (coalesced int4, swizzled)
#pragma unroll
    for (int i = 0; i < 2; ++i) {
        int ch = tid + 256 * i;
        int r = ch >> 4, c = ch & 15;
        int gr = row0 + r;
        int4 v = *(const int4*)(xbin + gr * H + c * 8);
        *(int4*)(&lds[r * H + ((c ^ (r & 15)) << 3)]) = v;
    }
    __syncthreads();  // waves flush rows filled by other waves' threads

    // Phase 0b: flat-range gather, accumulate into LDS rows
    {
        const int node0 = row0 + wave * 8;
        const int jb = __builtin_amdgcn_readfirstlane(offs[node0]);
        const int je = __builtin_amdgcn_readfirstlane(offs[node0 + 8]);
        int cur = wave * 8;          // current tile-local row (monotone)
        float a0 = 0.f, a1 = 0.f;
        if (jb < je) {
            u32 ce[16];
#pragma unroll
            for (int q = 0; q < 16; ++q) {
                int idx = jb + q;
                idx = idx < je ? idx : je - 1;
                ce[q] = (u32)__builtin_amdgcn_readfirstlane(colv[idx]);
            }
            for (int j = jb; j < je; j += 16) {
                u32 uu[16];
#pragma unroll
                for (int q = 0; q < 16; ++q)
                    uu[q] = *(const u32*)(xbin + (ce[q] & 0x1FFFFu) * H + lane * 2);
                u32 cn[16];  // prefetch next window's colv entries
#pragma unroll
                for (int q = 0; q < 16; ++q) {
                    int idx = j + 16 + q;
                    idx = idx < je ? idx : je - 1;
                    cn[q] = (u32)__builtin_amdgcn_readfirstlane(colv[idx]);
                }
#pragma unroll
                for (int q = 0; q < 16; ++q) {
                    if (j + q < je) {  // wave-uniform
                        int rloc = (int)(ce[q] >> 27);
                        if (rloc != cur) {  // flush completed row (once per row)
                            u16* p = &lds[cur * H + (((lane >> 2) ^ (cur & 15)) << 3) + ((lane & 3) << 1)];
                            u32 old = *(u32*)p;
                            *(u32*)p = (u32)f2bf(bflo(old) + a0) | ((u32)f2bf(bfhi(old) + a1) << 16);
                            a0 = 0.f; a1 = 0.f; cur = rloc;
                        }
                        a0 += bflo(uu[q]); a1 += bfhi(uu[q]);
                    }
                }
#pragma unroll
                for (int q = 0; q < 16; ++q) ce[q] = cn[q];
            }
        }
        // final flush (adds 0 if range empty — harmless)
        u16* p = &lds[cur * H + (((lane >> 2) ^ (cur & 15)) << 3) + ((lane & 3) << 1)];
        u32 old = *(u32*)p;
        *(u32*)p = (u32)f2bf(bflo(old) + a0) | ((u32)f2bf(bfhi(old) + a1) << 16);
    }

    // B1 fragments from global (L2-resident): B[k][n], n = wave*32+ml
    bf16x8 bfrag[8];
#pragma unroll
    for (int ks = 0; ks < 8; ++ks)
        bfrag[ks] = *(const bf16x8*)(wt1 + (wave * 32 + ml) * H + ks * 16 + g * 8);

    const float bias1 = b1[wave * 32 + ml];
    const float bias2 = b2[wave * 32 + ml];

    __syncthreads();

    f32x16 acc;
#pragma unroll
    for (int i = 0; i < 16; ++i) acc[i] = 0.f;

    // GEMM1: C[0:32][wave*32 .. +32]
#pragma unroll
    for (int ks = 0; ks < 8; ++ks) {
        int chunk = (2 * ks + g) ^ (ml & 15);
        bf16x8 afrag = *(const bf16x8*)(&lds[ml * H + (chunk << 3)]);
        acc = __builtin_amdgcn_mfma_f32_32x32x16_bf16(afrag, bfrag[ks], acc, 0, 0, 0);
    }

    __syncthreads();  // all A reads done before T overwrites LDS

    // T = relu(acc + b1) -> LDS (C-layout -> row-major[m][k], swizzled)
#pragma unroll
    for (int reg = 0; reg < 16; ++reg) {
        int rm = (reg & 3) + ((reg >> 2) << 3) + 4 * g;   // 0..31
        int cn = wave * 32 + ml;                           // 0..127
        float v = acc[reg] + bias1;
        v = v > 0.f ? v : 0.f;
        lds[rm * H + ((((cn >> 3) ^ (rm & 15))) << 3) + (cn & 7)] = f2bf(v);
    }

    // B2 fragments
#pragma unroll
    for (int ks = 0; ks < 8; ++ks)
        bfrag[ks] = *(const bf16x8*)(wt2 + (wave * 32 + ml) * H + ks * 16 + g * 8);

#pragma unroll
    for (int i = 0; i < 16; ++i) acc[i] = 0.f;

    __syncthreads();

    // GEMM2
#pragma unroll
    for (int ks = 0; ks < 8; ++ks) {
        int chunk = (2 * ks + g) ^ (ml & 15);
        bf16x8 afrag = *(const bf16x8*)(&lds[ml * H + (chunk << 3)]);
        acc = __builtin_amdgcn_mfma_f32_32x32x16_bf16(afrag, bfrag[ks], acc, 0, 0, 0);
    }

    __syncthreads();  // all T reads done before h overwrites LDS

    // h = relu(acc + b2) -> LDS (same swizzle)
#pragma unroll
    for (int reg = 0; reg < 16; ++reg) {
        int rm = (reg & 3) + ((reg >> 2) << 3) + 4 * g;
        int cn = wave * 32 + ml;
        float v = acc[reg] + bias2;
        v = v > 0.f ? v : 0.f;
        lds[rm * H + ((((cn >> 3) ^ (rm & 15))) << 3) + (cn & 7)] = f2bf(v);
    }

    __syncthreads();

    // coalesced residual update: x += h; xbout = bf16(x)
    // 32 rows x 16 chunks = 512 tasks, 2 per thread
#pragma unroll
    for (int i = 0; i < 2; ++i) {
        int ch = tid + 256 * i;
        int r = ch >> 4, c = ch & 15;
        int gr = row0 + r;
        int4 hv = *(const int4*)(&lds[r * H + ((c ^ (r & 15)) << 3)]);
        float4 x0 = *(const float4*)(x + gr * H + c * 8);
        float4 x1 = *(const float4*)(x + gr * H + c * 8 + 4);
        x0.x += bflo((u32)hv.x); x0.y += bfhi((u32)hv.x);
        x0.z += bflo((u32)hv.y); x0.w += bfhi((u32)hv.y);
        x1.x += bflo((u32)hv.z); x1.y += bfhi((u32)hv.z);
        x1.z += bflo((u32)hv.w); x1.w += bfhi((u32)hv.w);
        *(float4*)(x + gr * H + c * 8) = x0;
        *(float4*)(x + gr * H + c * 8 + 4) = x1;
        int4 xo;
        xo.x = (int)((u32)f2bf(x0.x) | ((u32)f2bf(x0.y) << 16));
        xo.y = (int)((u32)f2bf(x0.z) | ((u32)f2bf(x0.w) << 16));
        xo.z = (int)((u32)f2bf(x1.x) | ((u32)f2bf(x1.y) << 16));
        xo.w = (int)((u32)f2bf(x1.z) | ((u32)f2bf(x1.w) << 16));
        *(int4*)(xbout + gr * H + c * 8) = xo;
    }
}

extern "C" void kernel_launch(void* const* d_in, const int* in_sizes, int n_in,
                              void* d_out, int out_size, void* d_ws, size_t ws_size,
                              hipStream_t stream) {
    const float* x_in = (const float*)d_in[0];
    const int* edges = (const int*)d_in[1];
    const float* W1 = (const float*)d_in[2];
    const float* b1 = (const float*)d_in[3];
    const float* W2 = (const float*)d_in[4];
    const float* b2 = (const float*)d_in[5];
    float* x = (float*)d_out;

    char* ws = (char*)d_ws;
    int* flag = (int*)ws;                        // 4B        @ 0
    int* gcursor = (int*)(ws + 512);             // 784B      @ 512
    int* bbase = (int*)(ws + 2048);              // 784B      @ 2048
    int* offs = (int*)(ws + 4096);               // 400004B   @ 4096
    int* colv = (int*)(ws + 406528);             // 6400000B
    u16* wt = (u16*)(ws + 6809600);              // 262144B
    u16* xb0 = (u16*)(ws + 7072768);             // 25600000B
    u16* xb1 = (u16*)(ws + 32672768);            // 25600000B (end ~58.3MB)
    u32* ebuf = (u32*)xb1;                       // 8.03MB, dead before xb1 written

    detect_kernel<<<1, 256, 0, stream>>>(edges, flag, gcursor);
    part_kernel<<<PB_BLOCKS, 256, 0, stream>>>(edges, flag, gcursor, ebuf);
    bscan_kernel<<<1, 256, 0, stream>>>(gcursor, bbase, offs);
    bfill_kernel<<<NB, 256, 0, stream>>>(ebuf, gcursor, bbase, offs, colv);
    wtconv_kernel<<<131072 / 256, 256, 0, stream>>>(W1, W2, wt);
    xinit_kernel<<<(NN * H / 4) / 256, 256, 0, stream>>>(x_in, x, xb0);

    for (int l = 0; l < 4; ++l) {
        u16* xin = (l & 1) ? xb1 : xb0;
        u16* xout = (l & 1) ? xb0 : xb1;
        mlp_kernel<<<NN / 32, 256, 0, stream>>>(
            xin, colv, offs,
            wt + (l * 2) * 16384, wt + (l * 2 + 1) * 16384,
            b1 + l * 128, b2 + l * 128, x, xout);
    }
}

// Round 5
// 485.471 us; speedup vs baseline: 1.6366x; 1.0095x over previous
//
#include <hip/hip_runtime.h>

typedef unsigned short u16;
typedef unsigned int u32;
typedef unsigned char u8;

constexpr int NN = 100000;   // nodes
constexpr int NE = 1600000;  // edges
constexpr int H = 128;       // hidden

constexpr int NB = 196;      // coarse buckets: b = dst >> 9 (512 nodes/bucket)
constexpr int BCAP = 10240;  // per-bucket capacity (mean 8192, +22 sigma)
constexpr int PB_E = 4096;   // edges per partition block
constexpr int PB_BLOCKS = (NE + PB_E - 1) / PB_E;  // 391

typedef __bf16 bf16x8 __attribute__((ext_vector_type(8)));
typedef float f32x16 __attribute__((ext_vector_type(16)));

__device__ __forceinline__ u16 f2bf(float f) {
    union { float f; u32 u; } cv; cv.f = f;
    u32 r = (cv.u + 0x7fffu + ((cv.u >> 16) & 1u)) >> 16;
    return (u16)r;
}
__device__ __forceinline__ float bflo(u32 u) {
    union { u32 u; float f; } cv; cv.u = u << 16; return cv.f;
}
__device__ __forceinline__ float bfhi(u32 u) {
    union { u32 u; float f; } cv; cv.u = u & 0xffff0000u; return cv.f;
}

// ---- partition edges into NB dst-buckets (packed src|ldst) -------------------
// R10: LDS counting-sort staging. Old version scattered 4B writes across ~64
// buckets per wave (up to 16x line-granularity write amplification on 6.4MB).
// Now edges are ranked into a bucket-sorted LDS buffer and each bucket's run
// is written contiguously. Stride detection (int64 vs int32) is inlined: node
// ids < 2^31 so int64 high words are all zero; int32 odd words are src values.
__global__ __launch_bounds__(256) void part_kernel(const int* __restrict__ e,
                                                   int* __restrict__ gcursor,
                                                   u32* __restrict__ ebuf) {
    __shared__ int lcnt[256];
    __shared__ int ps[256];
    __shared__ int ex[256];
    __shared__ int gbaseL[NB];
    __shared__ int anynz;
    __shared__ u32 sbuf[PB_E];   // 16 KB
    __shared__ u8 sbk[PB_E];     // 4 KB
    const int t = threadIdx.x;
    if (t == 0) anynz = 0;
    lcnt[t] = 0;
    __syncthreads();
    int loc = 0;
    for (int i = t; i < 4096; i += 256) loc |= e[2 * i + 1];
    if (loc) atomicOr(&anynz, 1);
    __syncthreads();
    const int st = anynz ? 1 : 2;  // stride in int32 units
    const int base = blockIdx.x * PB_E;
    const int nval = (NE - base < PB_E) ? (NE - base) : PB_E;
    u32 pk[16]; int bk[16]; int rk[16];
#pragma unroll
    for (int j = 0; j < 16; ++j) {
        int i = base + j * 256 + t;
        bk[j] = -1;
        if (i < NE) {
            int s = e[st * i];
            int d = e[st * (NE + i)];
            int b = d >> 9;
            pk[j] = (u32)s | ((u32)(d & 511) << 17);
            bk[j] = b;
            rk[j] = atomicAdd(&lcnt[b], 1);
        }
    }
    __syncthreads();
    // exclusive scan of per-bucket counts
    int v = lcnt[t];
    ps[t] = v;
    __syncthreads();
    for (int off = 1; off < 256; off <<= 1) {
        int u = (t >= off) ? ps[t - off] : 0;
        __syncthreads();
        ps[t] += u;
        __syncthreads();
    }
    ex[t] = ps[t] - v;
    if (t < NB && v > 0) gbaseL[t] = atomicAdd(&gcursor[t], v);
    __syncthreads();
    // stage bucket-sorted
#pragma unroll
    for (int j = 0; j < 16; ++j)
        if (bk[j] >= 0) {
            int p = ex[bk[j]] + rk[j];
            sbuf[p] = pk[j];
            sbk[p] = (u8)bk[j];
        }
    __syncthreads();
    // coalesced write-out: consecutive i -> consecutive slot within a bucket run
    for (int i = t; i < nval; i += 256) {
        int b = sbk[i];
        ebuf[b * BCAP + gbaseL[b] + (i - ex[b])] = sbuf[i];
    }
}

// ---- exclusive scan of bucket totals ----------------------------------------
__global__ __launch_bounds__(256) void bscan_kernel(const int* __restrict__ gcursor,
                                                    int* __restrict__ bbase,
                                                    int* __restrict__ offs) {
    __shared__ int s[256];
    int t = threadIdx.x;
    int v = (t < NB) ? gcursor[t] : 0;
    s[t] = v;
    __syncthreads();
    for (int off = 1; off < 256; off <<= 1) {
        int u = (t >= off) ? s[t - off] : 0;
        __syncthreads();
        s[t] += u;
        __syncthreads();
    }
    if (t < NB) bbase[t] = s[t] - v;
    if (t == 0) offs[NN] = NE;
}

// ---- per-bucket CSR fill: LDS node counts/scan/cursors, local colv scatter ---
// colv entry packs src (bits 0..16) and tile-local dst row (bits 27..31,
// = dst & 31 for the BM=32 tiles) so the fused gather can route each edge to
// its LDS row with wave-uniform scalar ops.
__global__ __launch_bounds__(256) void bfill_kernel(const u32* __restrict__ ebuf,
                                                    const int* __restrict__ gcursor,
                                                    const int* __restrict__ bbase,
                                                    int* __restrict__ offs,
                                                    int* __restrict__ colv) {
    __shared__ int ncnt[512];
    __shared__ int cur[512];
    __shared__ int ps[256];
    const int b = blockIdx.x, t = threadIdx.x;
    const int En = gcursor[b];
    const int bb = bbase[b];
    ncnt[t] = 0; ncnt[t + 256] = 0;
    __syncthreads();
    const u32* eb = ebuf + b * BCAP;
    for (int i = t; i < En; i += 256)
        atomicAdd(&ncnt[eb[i] >> 17], 1);
    __syncthreads();
    int s2 = ncnt[2 * t] + ncnt[2 * t + 1];
    ps[t] = s2;
    __syncthreads();
    for (int off = 1; off < 256; off <<= 1) {
        int u = (t >= off) ? ps[t - off] : 0;
        __syncthreads();
        ps[t] += u;
        __syncthreads();
    }
    int e0 = ps[t] - s2;  // exclusive
    cur[2 * t] = e0;
    cur[2 * t + 1] = e0 + ncnt[2 * t];
    __syncthreads();
    const int n0 = b * 512;
    for (int i = t; i < 512; i += 256)
        if (n0 + i < NN) offs[n0 + i] = bb + cur[i];
    __syncthreads();  // offs reads of cur[] complete before pass2 mutates
    for (int i = t; i < En; i += 256) {
        u32 p = eb[i];
        int pos = atomicAdd(&cur[p >> 17], 1);
        colv[bb + pos] = (int)((p & 0x1FFFFu) | (((p >> 17) & 31u) << 27));
    }
}

// ---- fused init: weight transpose+convert / x copy + bf16 shadow ------------
// blocks [0,512): Wt[l*2+s][n][k] = W[l][k][n] (bf16)
// blocks [512, 512+12500): x copy + xb shadow
__global__ void init_kernel(const float* __restrict__ W1,
                            const float* __restrict__ W2,
                            u16* __restrict__ wt,
                            const float* __restrict__ xin,
                            float* __restrict__ x, u16* __restrict__ xb) {
    int b = blockIdx.x;
    if (b < 512) {
        int t = b * 256 + threadIdx.x;  // 131072 threads
        int w = t >> 14;      // 0..7 = l*2+s
        int r = t & 16383;
        int k = r >> 7, n = r & 127;  // n fastest -> coalesced reads
        int l = w >> 1, s = w & 1;
        const float* src = (s == 0 ? W1 : W2) + l * 16384;
        wt[w * 16384 + n * 128 + k] = f2bf(src[k * 128 + n]);
    } else {
        int i = (b - 512) * 256 + threadIdx.x;  // NN*H/4 threads
        float4 v = ((const float4*)xin)[i];
        ((float4*)x)[i] = v;
        uint2 p;
        p.x = (u32)f2bf(v.x) | ((u32)f2bf(v.y) << 16);
        p.y = (u32)f2bf(v.z) | ((u32)f2bf(v.w) << 16);
        ((uint2*)xb)[i] = p;
    }
}

// ---- fused layer: agg (gather into LDS) + MLP + residual --------------------
// R9/R10 structure: BM=32 tile, grid=3125, flat-range 16-deep gather with colv
// prefetch, wave-uniform row routing (colv bits 27..31), LDS pre-filled with
// self rows. R10: B1 fragments + biases hoisted ABOVE the gather so those L2
// loads overlap gather latency instead of serializing after it.
__global__ __launch_bounds__(256) void mlp_kernel(const u16* __restrict__ xbin,
                                                  const int* __restrict__ colv,
                                                  const int* __restrict__ offs,
                                                  const u16* __restrict__ wt1,
                                                  const u16* __restrict__ wt2,
                                                  const float* __restrict__ b1,
                                                  const float* __restrict__ b2,
                                                  float* __restrict__ x,
                                                  u16* __restrict__ xbout) {
    __shared__ u16 lds[32 * 128];  // 8 KB, XOR-swizzled 16B chunks
    const int tid = threadIdx.x;
    const int wave = tid >> 6, lane = tid & 63;
    const int ml = lane & 31, g = lane >> 5;
    const int row0 = blockIdx.x * 32;  // NN = 3125*32 exactly, no tail

    // B1 fragments + biases issued first: overlap with the gather below
    bf16x8 bfrag[8];
#pragma unroll
    for (int ks = 0; ks < 8; ++ks)
        bfrag[ks] = *(const bf16x8*)(wt1 + (wave * 32 + ml) * H + ks * 16 + g * 8);
    const float bias1 = b1[wave * 32 + ml];
    const float bias2 = b2[wave * 32 + ml];

    // Phase 0a: self rows -> LDS (coalesced int4, swizzled)
#pragma unroll
    for (int i = 0; i < 2; ++i) {
        int ch = tid + 256 * i;
        int r = ch >> 4, c = ch & 15;
        int gr = row0 + r;
        int4 v = *(const int4*)(xbin + gr * H + c * 8);
        *(int4*)(&lds[r * H + ((c ^ (r & 15)) << 3)]) = v;
    }
    __syncthreads();  // waves flush rows filled by other waves' threads

    // Phase 0b: flat-range gather, accumulate into LDS rows
    {
        const int node0 = row0 + wave * 8;
        const int jb = __builtin_amdgcn_readfirstlane(offs[node0]);
        const int je = __builtin_amdgcn_readfirstlane(offs[node0 + 8]);
        int cur = wave * 8;          // current tile-local row (monotone)
        float a0 = 0.f, a1 = 0.f;
        if (jb < je) {
            u32 ce[16];
#pragma unroll
            for (int q = 0; q < 16; ++q) {
                int idx = jb + q;
                idx = idx < je ? idx : je - 1;
                ce[q] = (u32)__builtin_amdgcn_readfirstlane(colv[idx]);
            }
            for (int j = jb; j < je; j += 16) {
                u32 uu[16];
#pragma unroll
                for (int q = 0; q < 16; ++q)
                    uu[q] = *(const u32*)(xbin + (ce[q] & 0x1FFFFu) * H + lane * 2);
                u32 cn[16];  // prefetch next window's colv entries
#pragma unroll
                for (int q = 0; q < 16; ++q) {
                    int idx = j + 16 + q;
                    idx = idx < je ? idx : je - 1;
                    cn[q] = (u32)__builtin_amdgcn_readfirstlane(colv[idx]);
                }
#pragma unroll
                for (int q = 0; q < 16; ++q) {
                    if (j + q < je) {  // wave-uniform
                        int rloc = (int)(ce[q] >> 27);
                        if (rloc != cur) {  // flush completed row (once per row)
                            u16* p = &lds[cur * H + (((lane >> 2) ^ (cur & 15)) << 3) + ((lane & 3) << 1)];
                            u32 old = *(u32*)p;
                            *(u32*)p = (u32)f2bf(bflo(old) + a0) | ((u32)f2bf(bfhi(old) + a1) << 16);
                            a0 = 0.f; a1 = 0.f; cur = rloc;
                        }
                        a0 += bflo(uu[q]); a1 += bfhi(uu[q]);
                    }
                }
#pragma unroll
                for (int q = 0; q < 16; ++q) ce[q] = cn[q];
            }
        }
        // final flush (adds 0 if range empty — harmless)
        u16* p = &lds[cur * H + (((lane >> 2) ^ (cur & 15)) << 3) + ((lane & 3) << 1)];
        u32 old = *(u32*)p;
        *(u32*)p = (u32)f2bf(bflo(old) + a0) | ((u32)f2bf(bfhi(old) + a1) << 16);
    }

    __syncthreads();

    f32x16 acc;
#pragma unroll
    for (int i = 0; i < 16; ++i) acc[i] = 0.f;

    // GEMM1: C[0:32][wave*32 .. +32]
#pragma unroll
    for (int ks = 0; ks < 8; ++ks) {
        int chunk = (2 * ks + g) ^ (ml & 15);
        bf16x8 afrag = *(const bf16x8*)(&lds[ml * H + (chunk << 3)]);
        acc = __builtin_amdgcn_mfma_f32_32x32x16_bf16(afrag, bfrag[ks], acc, 0, 0, 0);
    }

    __syncthreads();  // all A reads done before T overwrites LDS

    // T = relu(acc + b1) -> LDS (C-layout -> row-major[m][k], swizzled)
#pragma unroll
    for (int reg = 0; reg < 16; ++reg) {
        int rm = (reg & 3) + ((reg >> 2) << 3) + 4 * g;   // 0..31
        int cn = wave * 32 + ml;                           // 0..127
        float v = acc[reg] + bias1;
        v = v > 0.f ? v : 0.f;
        lds[rm * H + ((((cn >> 3) ^ (rm & 15))) << 3) + (cn & 7)] = f2bf(v);
    }

    // B2 fragments
#pragma unroll
    for (int ks = 0; ks < 8; ++ks)
        bfrag[ks] = *(const bf16x8*)(wt2 + (wave * 32 + ml) * H + ks * 16 + g * 8);

#pragma unroll
    for (int i = 0; i < 16; ++i) acc[i] = 0.f;

    __syncthreads();

    // GEMM2
#pragma unroll
    for (int ks = 0; ks < 8; ++ks) {
        int chunk = (2 * ks + g) ^ (ml & 15);
        bf16x8 afrag = *(const bf16x8*)(&lds[ml * H + (chunk << 3)]);
        acc = __builtin_amdgcn_mfma_f32_32x32x16_bf16(afrag, bfrag[ks], acc, 0, 0, 0);
    }

    __syncthreads();  // all T reads done before h overwrites LDS

    // h = relu(acc + b2) -> LDS (same swizzle)
#pragma unroll
    for (int reg = 0; reg < 16; ++reg) {
        int rm = (reg & 3) + ((reg >> 2) << 3) + 4 * g;
        int cn = wave * 32 + ml;
        float v = acc[reg] + bias2;
        v = v > 0.f ? v : 0.f;
        lds[rm * H + ((((cn >> 3) ^ (rm & 15))) << 3) + (cn & 7)] = f2bf(v);
    }

    __syncthreads();

    // coalesced residual update: x += h; xbout = bf16(x)
    // 32 rows x 16 chunks = 512 tasks, 2 per thread
#pragma unroll
    for (int i = 0; i < 2; ++i) {
        int ch = tid + 256 * i;
        int r = ch >> 4, c = ch & 15;
        int gr = row0 + r;
        int4 hv = *(const int4*)(&lds[r * H + ((c ^ (r & 15)) << 3)]);
        float4 x0 = *(const float4*)(x + gr * H + c * 8);
        float4 x1 = *(const float4*)(x + gr * H + c * 8 + 4);
        x0.x += bflo((u32)hv.x); x0.y += bfhi((u32)hv.x);
        x0.z += bflo((u32)hv.y); x0.w += bfhi((u32)hv.y);
        x1.x += bflo((u32)hv.z); x1.y += bfhi((u32)hv.z);
        x1.z += bflo((u32)hv.w); x1.w += bfhi((u32)hv.w);
        *(float4*)(x + gr * H + c * 8) = x0;
        *(float4*)(x + gr * H + c * 8 + 4) = x1;
        int4 xo;
        xo.x = (int)((u32)f2bf(x0.x) | ((u32)f2bf(x0.y) << 16));
        xo.y = (int)((u32)f2bf(x0.z) | ((u32)f2bf(x0.w) << 16));
        xo.z = (int)((u32)f2bf(x1.x) | ((u32)f2bf(x1.y) << 16));
        xo.w = (int)((u32)f2bf(x1.z) | ((u32)f2bf(x1.w) << 16));
        *(int4*)(xbout + gr * H + c * 8) = xo;
    }
}

extern "C" void kernel_launch(void* const* d_in, const int* in_sizes, int n_in,
                              void* d_out, int out_size, void* d_ws, size_t ws_size,
                              hipStream_t stream) {
    const float* x_in = (const float*)d_in[0];
    const int* edges = (const int*)d_in[1];
    const float* W1 = (const float*)d_in[2];
    const float* b1 = (const float*)d_in[3];
    const float* W2 = (const float*)d_in[4];
    const float* b2 = (const float*)d_in[5];
    float* x = (float*)d_out;

    char* ws = (char*)d_ws;
    int* gcursor = (int*)(ws + 512);             // 784B      @ 512
    int* bbase = (int*)(ws + 2048);              // 784B      @ 2048
    int* offs = (int*)(ws + 4096);               // 400004B   @ 4096
    int* colv = (int*)(ws + 406528);             // 6400000B
    u16* wt = (u16*)(ws + 6809600);              // 262144B
    u16* xb0 = (u16*)(ws + 7072768);             // 25600000B
    u16* xb1 = (u16*)(ws + 32672768);            // 25600000B (end ~58.3MB)
    u32* ebuf = (u32*)xb1;                       // 8.03MB, dead before xb1 written

    hipMemsetAsync(gcursor, 0, NB * sizeof(int), stream);
    part_kernel<<<PB_BLOCKS, 256, 0, stream>>>(edges, gcursor, ebuf);
    bscan_kernel<<<1, 256, 0, stream>>>(gcursor, bbase, offs);
    bfill_kernel<<<NB, 256, 0, stream>>>(ebuf, gcursor, bbase, offs, colv);
    init_kernel<<<512 + (NN * H / 4) / 256, 256, 0, stream>>>(W1, W2, wt, x_in, x, xb0);

    for (int l = 0; l < 4; ++l) {
        u16* xin = (l & 1) ? xb1 : xb0;
        u16* xout = (l & 1) ? xb0 : xb1;
        mlp_kernel<<<NN / 32, 256, 0, stream>>>(
            xin, colv, offs,
            wt + (l * 2) * 16384, wt + (l * 2 + 1) * 16384,
            b1 + l * 128, b2 + l * 128, x, xout);
    }
}

// Round 6
// 464.897 us; speedup vs baseline: 1.7090x; 1.0443x over previous
//
#include <hip/hip_runtime.h>

typedef unsigned short u16;
typedef unsigned int u32;
typedef unsigned char u8;

constexpr int NN = 100000;   // nodes
constexpr int NE = 1600000;  // edges
constexpr int H = 128;       // hidden

constexpr int NB = 196;      // coarse buckets: b = dst >> 9 (512 nodes/bucket)
constexpr int BCAP = 10240;  // per-bucket capacity (mean 8192, +22 sigma)
constexpr int PB_E = 4096;   // edges per partition block
constexpr int PB_BLOCKS = (NE + PB_E - 1) / PB_E;  // 391
constexpr int WT_BLOCKS = 512;
constexpr int XI_BLOCKS = (NN * H / 4) / 256;      // 12500

typedef __bf16 bf16x8 __attribute__((ext_vector_type(8)));
typedef float f32x16 __attribute__((ext_vector_type(16)));

__device__ __forceinline__ u16 f2bf(float f) {
    union { float f; u32 u; } cv; cv.f = f;
    u32 r = (cv.u + 0x7fffu + ((cv.u >> 16) & 1u)) >> 16;
    return (u16)r;
}
__device__ __forceinline__ float bflo(u32 u) {
    union { u32 u; float f; } cv; cv.u = u << 16; return cv.f;
}
__device__ __forceinline__ float bfhi(u32 u) {
    union { u32 u; float f; } cv; cv.u = u & 0xffff0000u; return cv.f;
}
// pack two floats -> two bf16 (lo|hi<<16)
__device__ __forceinline__ u32 pkbf(float a, float b) {
    return (u32)f2bf(a) | ((u32)f2bf(b) << 16);
}

// ---- fused preproc: edge partition / weight transpose / x init --------------
// blocks [0,391): LDS counting-sort partition of edges into NB dst-buckets.
// blocks [391,903): Wt[l*2+s][n][k] = W[l][k][n] (bf16)
// blocks [903,13403): x shadow init (MODE1: hi/lo bf16 pair; MODE0: +fp32 copy)
__global__ __launch_bounds__(256) void preproc_kernel(const int* __restrict__ e,
                                                      int* __restrict__ gcursor,
                                                      u32* __restrict__ ebuf,
                                                      const float* __restrict__ W1,
                                                      const float* __restrict__ W2,
                                                      u16* __restrict__ wt,
                                                      const float* __restrict__ xin,
                                                      float* __restrict__ x,
                                                      u16* __restrict__ xb,
                                                      u16* __restrict__ xe,
                                                      int mode) {
    __shared__ int lcnt[256];
    __shared__ int ps[256];
    __shared__ int ex[256];
    __shared__ int gbaseL[NB];
    __shared__ int anynz;
    __shared__ u32 sbuf[PB_E];   // 16 KB
    __shared__ u8 sbk[PB_E];     // 4 KB
    const int blk = blockIdx.x;
    const int t = threadIdx.x;

    if (blk >= PB_BLOCKS) {
        if (blk < PB_BLOCKS + WT_BLOCKS) {
            int tt = (blk - PB_BLOCKS) * 256 + t;  // 131072 threads
            int w = tt >> 14;      // 0..7 = l*2+s
            int r = tt & 16383;
            int k = r >> 7, n = r & 127;  // n fastest -> coalesced reads
            int l = w >> 1, s = w & 1;
            const float* src = (s == 0 ? W1 : W2) + l * 16384;
            wt[w * 16384 + n * 128 + k] = f2bf(src[k * 128 + n]);
        } else {
            int i = (blk - PB_BLOCKS - WT_BLOCKS) * 256 + t;  // NN*H/4 threads
            float4 v = ((const float4*)xin)[i];
            uint2 p;
            p.x = pkbf(v.x, v.y);
            p.y = pkbf(v.z, v.w);
            ((uint2*)xb)[i] = p;
            if (mode == 1) {
                // compensation term: lo = bf16(v - float(hi))
                uint2 q;
                q.x = pkbf(v.x - bflo(p.x), v.y - bfhi(p.x));
                q.y = pkbf(v.z - bflo(p.y), v.w - bfhi(p.y));
                ((uint2*)xe)[i] = q;
            } else {
                ((float4*)x)[i] = v;
            }
        }
        return;
    }

    // ---- edge partition branch (LDS counting sort; R10 structure) ----
    if (t == 0) anynz = 0;
    lcnt[t] = 0;
    __syncthreads();
    int loc = 0;
    for (int i = t; i < 4096; i += 256) loc |= e[2 * i + 1];
    if (loc) atomicOr(&anynz, 1);
    __syncthreads();
    const int st = anynz ? 1 : 2;  // stride in int32 units (int32 vs int64 input)
    const int base = blk * PB_E;
    const int nval = (NE - base < PB_E) ? (NE - base) : PB_E;
    u32 pk[16]; int bk[16]; int rk[16];
#pragma unroll
    for (int j = 0; j < 16; ++j) {
        int i = base + j * 256 + t;
        bk[j] = -1;
        if (i < NE) {
            int s = e[st * i];
            int d = e[st * (NE + i)];
            int b = d >> 9;
            pk[j] = (u32)s | ((u32)(d & 511) << 17);
            bk[j] = b;
            rk[j] = atomicAdd(&lcnt[b], 1);
        }
    }
    __syncthreads();
    int v = lcnt[t];
    ps[t] = v;
    __syncthreads();
    for (int off = 1; off < 256; off <<= 1) {
        int u = (t >= off) ? ps[t - off] : 0;
        __syncthreads();
        ps[t] += u;
        __syncthreads();
    }
    ex[t] = ps[t] - v;
    if (t < NB && v > 0) gbaseL[t] = atomicAdd(&gcursor[t], v);
    __syncthreads();
#pragma unroll
    for (int j = 0; j < 16; ++j)
        if (bk[j] >= 0) {
            int p = ex[bk[j]] + rk[j];
            sbuf[p] = pk[j];
            sbk[p] = (u8)bk[j];
        }
    __syncthreads();
    for (int i = t; i < nval; i += 256) {
        int b = sbk[i];
        ebuf[b * BCAP + gbaseL[b] + (i - ex[b])] = sbuf[i];
    }
}

// ---- per-bucket CSR fill (bscan folded in: each block scans the 196 counts) -
// colv entry packs src (bits 0..16) and tile-local dst row (bits 27..31).
__global__ __launch_bounds__(256) void bfill_kernel(const u32* __restrict__ ebuf,
                                                    const int* __restrict__ gcursor,
                                                    int* __restrict__ offs,
                                                    int* __restrict__ colv) {
    __shared__ int ncnt[512];
    __shared__ int cur[512];
    __shared__ int ps[256];
    const int b = blockIdx.x, t = threadIdx.x;
    const int En = gcursor[b];
    // local exclusive scan of bucket totals -> bb (replaces bscan_kernel)
    int gv = (t < NB) ? gcursor[t] : 0;
    ps[t] = gv;
    __syncthreads();
    for (int off = 1; off < 256; off <<= 1) {
        int u = (t >= off) ? ps[t - off] : 0;
        __syncthreads();
        ps[t] += u;
        __syncthreads();
    }
    const int bb = ps[b] - En;  // exclusive prefix of this bucket
    if (b == 0 && t == 0) offs[NN] = NE;
    ncnt[t] = 0; ncnt[t + 256] = 0;
    __syncthreads();  // also separates ps reads from the reuse below
    const u32* eb = ebuf + b * BCAP;
    for (int i = t; i < En; i += 256)
        atomicAdd(&ncnt[eb[i] >> 17], 1);
    __syncthreads();
    int s2 = ncnt[2 * t] + ncnt[2 * t + 1];
    ps[t] = s2;
    __syncthreads();
    for (int off = 1; off < 256; off <<= 1) {
        int u = (t >= off) ? ps[t - off] : 0;
        __syncthreads();
        ps[t] += u;
        __syncthreads();
    }
    int e0 = ps[t] - s2;  // exclusive
    cur[2 * t] = e0;
    cur[2 * t + 1] = e0 + ncnt[2 * t];
    __syncthreads();
    const int n0 = b * 512;
    for (int i = t; i < 512; i += 256)
        if (n0 + i < NN) offs[n0 + i] = bb + cur[i];
    __syncthreads();  // offs reads of cur[] complete before pass2 mutates
    for (int i = t; i < En; i += 256) {
        u32 p = eb[i];
        int pos = atomicAdd(&cur[p >> 17], 1);
        colv[bb + pos] = (int)((p & 0x1FFFFu) | (((p >> 17) & 31u) << 27));
    }
}

// ---- fused layer: agg (gather into LDS) + MLP + residual --------------------
// R11: MODE=1 replaces the fp32 x RMW (102.4MB/layer) with a compensated bf16
// state pair: x ~= float(hi)+float(lo), hi = gathered xb (double-buffered),
// lo = self-only in-place buffer. Layers 0-2 write hi+lo; the LAST layer
// writes fp32 x = hi+lo+relu(h) (d_out written exactly once). Self hi rows
// are stashed in registers during phase 0a. MODE=0 = legacy fp32-RMW path
// (used when ws_size can't hold the lo buffer).
template <int MODE, bool LAST>
__global__ __launch_bounds__(256) void mlp_kernel(const u16* __restrict__ xbin,
                                                  const int* __restrict__ colv,
                                                  const int* __restrict__ offs,
                                                  const u16* __restrict__ wt1,
                                                  const u16* __restrict__ wt2,
                                                  const float* __restrict__ b1,
                                                  const float* __restrict__ b2,
                                                  float* __restrict__ x,
                                                  u16* __restrict__ xbout,
                                                  u16* __restrict__ xe) {
    __shared__ u16 lds[32 * 128];  // 8 KB, XOR-swizzled 16B chunks
    const int tid = threadIdx.x;
    const int wave = tid >> 6, lane = tid & 63;
    const int ml = lane & 31, g = lane >> 5;
    const int row0 = blockIdx.x * 32;  // NN = 3125*32 exactly, no tail

    // Phase 0a: self rows -> LDS (coalesced int4, swizzled); stash in regs
    int4 sv[2];
#pragma unroll
    for (int i = 0; i < 2; ++i) {
        int ch = tid + 256 * i;
        int r = ch >> 4, c = ch & 15;
        int gr = row0 + r;
        int4 v = *(const int4*)(xbin + gr * H + c * 8);
        sv[i] = v;
        *(int4*)(&lds[r * H + ((c ^ (r & 15)) << 3)]) = v;
    }
    __syncthreads();

    // Phase 0b: flat-range gather, accumulate into LDS rows
    {
        const int node0 = row0 + wave * 8;
        const int jb = __builtin_amdgcn_readfirstlane(offs[node0]);
        const int je = __builtin_amdgcn_readfirstlane(offs[node0 + 8]);
        int cur = wave * 8;          // current tile-local row (monotone)
        float a0 = 0.f, a1 = 0.f;
        if (jb < je) {
            u32 ce[16];
#pragma unroll
            for (int q = 0; q < 16; ++q) {
                int idx = jb + q;
                idx = idx < je ? idx : je - 1;
                ce[q] = (u32)__builtin_amdgcn_readfirstlane(colv[idx]);
            }
            for (int j = jb; j < je; j += 16) {
                u32 uu[16];
#pragma unroll
                for (int q = 0; q < 16; ++q)
                    uu[q] = *(const u32*)(xbin + (ce[q] & 0x1FFFFu) * H + lane * 2);
                u32 cn[16];  // prefetch next window's colv entries
#pragma unroll
                for (int q = 0; q < 16; ++q) {
                    int idx = j + 16 + q;
                    idx = idx < je ? idx : je - 1;
                    cn[q] = (u32)__builtin_amdgcn_readfirstlane(colv[idx]);
                }
#pragma unroll
                for (int q = 0; q < 16; ++q) {
                    if (j + q < je) {  // wave-uniform
                        int rloc = (int)(ce[q] >> 27);
                        if (rloc != cur) {  // flush completed row (once per row)
                            u16* p = &lds[cur * H + (((lane >> 2) ^ (cur & 15)) << 3) + ((lane & 3) << 1)];
                            u32 old = *(u32*)p;
                            *(u32*)p = pkbf(bflo(old) + a0, bfhi(old) + a1);
                            a0 = 0.f; a1 = 0.f; cur = rloc;
                        }
                        a0 += bflo(uu[q]); a1 += bfhi(uu[q]);
                    }
                }
#pragma unroll
                for (int q = 0; q < 16; ++q) ce[q] = cn[q];
            }
        }
        u16* p = &lds[cur * H + (((lane >> 2) ^ (cur & 15)) << 3) + ((lane & 3) << 1)];
        u32 old = *(u32*)p;
        *(u32*)p = pkbf(bflo(old) + a0, bfhi(old) + a1);
    }

    // B1 fragments + biases (R4 position: after gather — R5 hoist regressed)
    bf16x8 bfrag[8];
#pragma unroll
    for (int ks = 0; ks < 8; ++ks)
        bfrag[ks] = *(const bf16x8*)(wt1 + (wave * 32 + ml) * H + ks * 16 + g * 8);
    const float bias1 = b1[wave * 32 + ml];
    const float bias2 = b2[wave * 32 + ml];

    __syncthreads();

    f32x16 acc;
#pragma unroll
    for (int i = 0; i < 16; ++i) acc[i] = 0.f;

    // GEMM1: C[0:32][wave*32 .. +32]
#pragma unroll
    for (int ks = 0; ks < 8; ++ks) {
        int chunk = (2 * ks + g) ^ (ml & 15);
        bf16x8 afrag = *(const bf16x8*)(&lds[ml * H + (chunk << 3)]);
        acc = __builtin_amdgcn_mfma_f32_32x32x16_bf16(afrag, bfrag[ks], acc, 0, 0, 0);
    }

    __syncthreads();  // all A reads done before T overwrites LDS

    // T = relu(acc + b1) -> LDS (C-layout -> row-major[m][k], swizzled)
#pragma unroll
    for (int reg = 0; reg < 16; ++reg) {
        int rm = (reg & 3) + ((reg >> 2) << 3) + 4 * g;   // 0..31
        int cn = wave * 32 + ml;                           // 0..127
        float v = acc[reg] + bias1;
        v = v > 0.f ? v : 0.f;
        lds[rm * H + ((((cn >> 3) ^ (rm & 15))) << 3) + (cn & 7)] = f2bf(v);
    }

    // B2 fragments
#pragma unroll
    for (int ks = 0; ks < 8; ++ks)
        bfrag[ks] = *(const bf16x8*)(wt2 + (wave * 32 + ml) * H + ks * 16 + g * 8);

#pragma unroll
    for (int i = 0; i < 16; ++i) acc[i] = 0.f;

    __syncthreads();

    // GEMM2
#pragma unroll
    for (int ks = 0; ks < 8; ++ks) {
        int chunk = (2 * ks + g) ^ (ml & 15);
        bf16x8 afrag = *(const bf16x8*)(&lds[ml * H + (chunk << 3)]);
        acc = __builtin_amdgcn_mfma_f32_32x32x16_bf16(afrag, bfrag[ks], acc, 0, 0, 0);
    }

    __syncthreads();  // all T reads done before h overwrites LDS

    // h = relu(acc + b2) -> LDS (same swizzle)
#pragma unroll
    for (int reg = 0; reg < 16; ++reg) {
        int rm = (reg & 3) + ((reg >> 2) << 3) + 4 * g;
        int cn = wave * 32 + ml;
        float v = acc[reg] + bias2;
        v = v > 0.f ? v : 0.f;
        lds[rm * H + ((((cn >> 3) ^ (rm & 15))) << 3) + (cn & 7)] = f2bf(v);
    }

    __syncthreads();

    // epilogue: residual update
#pragma unroll
    for (int i = 0; i < 2; ++i) {
        int ch = tid + 256 * i;
        int r = ch >> 4, c = ch & 15;
        int gr = row0 + r;
        int4 hv = *(const int4*)(&lds[r * H + ((c ^ (r & 15)) << 3)]);
        if constexpr (MODE == 1) {
            int4 se = sv[i];  // self hi (stashed bf16 pairs)
            int4 le = *(const int4*)(xe + gr * H + c * 8);  // self lo
            float xn[8];
            xn[0] = bflo((u32)se.x) + bflo((u32)le.x) + bflo((u32)hv.x);
            xn[1] = bfhi((u32)se.x) + bfhi((u32)le.x) + bfhi((u32)hv.x);
            xn[2] = bflo((u32)se.y) + bflo((u32)le.y) + bflo((u32)hv.y);
            xn[3] = bfhi((u32)se.y) + bfhi((u32)le.y) + bfhi((u32)hv.y);
            xn[4] = bflo((u32)se.z) + bflo((u32)le.z) + bflo((u32)hv.z);
            xn[5] = bfhi((u32)se.z) + bfhi((u32)le.z) + bfhi((u32)hv.z);
            xn[6] = bflo((u32)se.w) + bflo((u32)le.w) + bflo((u32)hv.w);
            xn[7] = bfhi((u32)se.w) + bfhi((u32)le.w) + bfhi((u32)hv.w);
            if constexpr (LAST) {
                float4 o0 = make_float4(xn[0], xn[1], xn[2], xn[3]);
                float4 o1 = make_float4(xn[4], xn[5], xn[6], xn[7]);
                *(float4*)(x + gr * H + c * 8) = o0;
                *(float4*)(x + gr * H + c * 8 + 4) = o1;
            } else {
                int4 ho, lo4;
                u32 h0, h1;
                h0 = pkbf(xn[0], xn[1]); ho.x = (int)h0;
                lo4.x = (int)pkbf(xn[0] - bflo(h0), xn[1] - bfhi(h0));
                h1 = pkbf(xn[2], xn[3]); ho.y = (int)h1;
                lo4.y = (int)pkbf(xn[2] - bflo(h1), xn[3] - bfhi(h1));
                h0 = pkbf(xn[4], xn[5]); ho.z = (int)h0;
                lo4.z = (int)pkbf(xn[4] - bflo(h0), xn[5] - bfhi(h0));
                h1 = pkbf(xn[6], xn[7]); ho.w = (int)h1;
                lo4.w = (int)pkbf(xn[6] - bflo(h1), xn[7] - bfhi(h1));
                *(int4*)(xbout + gr * H + c * 8) = ho;
                *(int4*)(xe + gr * H + c * 8) = lo4;
            }
        } else {
            float4 x0 = *(const float4*)(x + gr * H + c * 8);
            float4 x1 = *(const float4*)(x + gr * H + c * 8 + 4);
            x0.x += bflo((u32)hv.x); x0.y += bfhi((u32)hv.x);
            x0.z += bflo((u32)hv.y); x0.w += bfhi((u32)hv.y);
            x1.x += bflo((u32)hv.z); x1.y += bfhi((u32)hv.z);
            x1.z += bflo((u32)hv.w); x1.w += bfhi((u32)hv.w);
            *(float4*)(x + gr * H + c * 8) = x0;
            *(float4*)(x + gr * H + c * 8 + 4) = x1;
            int4 xo;
            xo.x = (int)pkbf(x0.x, x0.y);
            xo.y = (int)pkbf(x0.z, x0.w);
            xo.z = (int)pkbf(x1.x, x1.y);
            xo.w = (int)pkbf(x1.z, x1.w);
            *(int4*)(xbout + gr * H + c * 8) = xo;
        }
    }
}

extern "C" void kernel_launch(void* const* d_in, const int* in_sizes, int n_in,
                              void* d_out, int out_size, void* d_ws, size_t ws_size,
                              hipStream_t stream) {
    const float* x_in = (const float*)d_in[0];
    const int* edges = (const int*)d_in[1];
    const float* W1 = (const float*)d_in[2];
    const float* b1 = (const float*)d_in[3];
    const float* W2 = (const float*)d_in[4];
    const float* b2 = (const float*)d_in[5];
    float* x = (float*)d_out;

    char* ws = (char*)d_ws;
    int* gcursor = (int*)(ws + 512);             // 784B      @ 512
    int* offs = (int*)(ws + 4096);               // 400004B   @ 4096
    int* colv = (int*)(ws + 406528);             // 6400000B
    u16* wt = (u16*)(ws + 6809600);              // 262144B
    u16* xb0 = (u16*)(ws + 7072768);             // 25600000B
    u16* xb1 = (u16*)(ws + 32672768);            // 25600000B
    u16* xe = (u16*)(ws + 58272768);             // 25600000B (MODE1; end 83.9MB)
    u32* ebuf = (u32*)xb1;                       // 8.03MB, dead before xb1 written

    const bool big = ws_size >= (size_t)83872768;
    const int mode = big ? 1 : 0;

    hipMemsetAsync(gcursor, 0, NB * sizeof(int), stream);
    preproc_kernel<<<PB_BLOCKS + WT_BLOCKS + XI_BLOCKS, 256, 0, stream>>>(
        edges, gcursor, ebuf, W1, W2, wt, x_in, x, xb0, xe, mode);
    bfill_kernel<<<NB, 256, 0, stream>>>(ebuf, gcursor, offs, colv);

    for (int l = 0; l < 4; ++l) {
        u16* xin = (l & 1) ? xb1 : xb0;
        u16* xout = (l & 1) ? xb0 : xb1;
        const u16* w1p = wt + (l * 2) * 16384;
        const u16* w2p = wt + (l * 2 + 1) * 16384;
        const float* b1p = b1 + l * 128;
        const float* b2p = b2 + l * 128;
        if (big) {
            if (l < 3)
                mlp_kernel<1, false><<<NN / 32, 256, 0, stream>>>(
                    xin, colv, offs, w1p, w2p, b1p, b2p, x, xout, xe);
            else
                mlp_kernel<1, true><<<NN / 32, 256, 0, stream>>>(
                    xin, colv, offs, w1p, w2p, b1p, b2p, x, xout, xe);
        } else {
            mlp_kernel<0, false><<<NN / 32, 256, 0, stream>>>(
                xin, colv, offs, w1p, w2p, b1p, b2p, x, xout, xb0 /*unused*/);
        }
    }
}